// Round 10
// baseline (605.823 us; speedup 1.0000x reference)
//
#include <hip/hip_runtime.h>
#include <hip/hip_bf16.h>
#include <math.h>

#define NHEADS 4
#define DOUT 16
#define EDIM 5
#define CAP 128   // per-node edge capacity for the LDS fast path

// ---------------------------------------------------------------------------
// K1: feat_p = feat @ W_fc  (N x 64 @ 64 x 64), fused el/er attention dots.
// One wave per node; lane j owns output feature j (= h*16+d).
// ---------------------------------------------------------------------------
__global__ __launch_bounds__(256) void node_proj_kernel(
    const float* __restrict__ feat, const float* __restrict__ W_fc,
    const float* __restrict__ attn_l, const float* __restrict__ attn_r,
    float* __restrict__ feat_p, float* __restrict__ el_er, int N) {
  __shared__ float wfc[64 * 64];
  for (int i = threadIdx.x; i < 64 * 64; i += 256) wfc[i] = W_fc[i];
  __syncthreads();
  const int wid  = threadIdx.x >> 6;
  const int lane = threadIdx.x & 63;
  const int n = blockIdx.x * 4 + wid;
  if (n >= N) return;

  const float f = feat[(size_t)n * 64 + lane];
  float acc = 0.f;
#pragma unroll
  for (int k = 0; k < 64; ++k) {
    const float fk = __shfl(f, k);
    acc += fk * wfc[k * 64 + lane];
  }
  feat_p[(size_t)n * 64 + lane] = acc;

  float al = acc * attn_l[lane];
  float ar = acc * attn_r[lane];
#pragma unroll
  for (int off = 1; off < 16; off <<= 1) {
    al += __shfl_xor(al, off);
    ar += __shfl_xor(ar, off);
  }
  if ((lane & 15) == 0) {
    const int h = lane >> 4;
    el_er[(size_t)n * 8 + h]     = al;
    el_er[(size_t)n * 8 + 4 + h] = ar;
  }
}

// ---------------------------------------------------------------------------
// K2: dst histogram only (atomic return value = CSR rank).
// ---------------------------------------------------------------------------
__global__ __launch_bounds__(256) void rank_kernel(
    const int* __restrict__ dst, int* __restrict__ deg,
    int* __restrict__ rank, int E) {
  const int e = blockIdx.x * blockDim.x + threadIdx.x;
  if (e >= E) return;
  rank[e] = atomicAdd(&deg[dst[e]], 1);
}

// ---------------------------------------------------------------------------
// K3a/K3b/K3c: hierarchical exclusive scan of deg[N] -> row_off[N+1].
// ---------------------------------------------------------------------------
__global__ __launch_bounds__(256) void scan_reduce_kernel(
    const int* __restrict__ deg, int* __restrict__ partial, int N) {
  const int base = blockIdx.x * 1024;
  int sum = 0;
  for (int i = threadIdx.x; i < 1024; i += 256) {
    const int idx = base + i;
    sum += (idx < N) ? deg[idx] : 0;
  }
#pragma unroll
  for (int off = 32; off >= 1; off >>= 1) sum += __shfl_xor(sum, off);
  __shared__ int ws[4];
  if ((threadIdx.x & 63) == 0) ws[threadIdx.x >> 6] = sum;
  __syncthreads();
  if (threadIdx.x == 0) partial[blockIdx.x] = ws[0] + ws[1] + ws[2] + ws[3];
}

__global__ __launch_bounds__(256) void scan_partials_kernel(
    int* __restrict__ partial, int nb) {
  __shared__ int buf[256];
  __shared__ int carry_s;
  const int t = threadIdx.x;
  if (t == 0) carry_s = 0;
  __syncthreads();
  for (int base = 0; base < nb; base += 256) {
    const int i = base + t;
    const int v = (i < nb) ? partial[i] : 0;
    buf[t] = v;
    __syncthreads();
    for (int off = 1; off < 256; off <<= 1) {
      const int tmp = (t >= off) ? buf[t - off] : 0;
      __syncthreads();
      buf[t] += tmp;
      __syncthreads();
    }
    const int carry = carry_s;
    if (i < nb) partial[i] = carry + buf[t] - v;  // exclusive
    __syncthreads();
    if (t == 255) carry_s = carry + buf[255];
    __syncthreads();
  }
}

__global__ __launch_bounds__(256) void scan_final_kernel(
    const int* __restrict__ deg, const int* __restrict__ partial,
    int* __restrict__ row_off, int N, int E) {
  const int b = blockIdx.x;
  const int t = threadIdx.x;
  const int lane = t & 63;
  const int wid = t >> 6;
  const int base = b * 1024 + t * 4;
  int v[4];
#pragma unroll
  for (int q = 0; q < 4; ++q) {
    const int idx = base + q;
    v[q] = (idx < N) ? deg[idx] : 0;
  }
  const int tsum = v[0] + v[1] + v[2] + v[3];
  int x = tsum;
#pragma unroll
  for (int off = 1; off < 64; off <<= 1) {
    const int tt = __shfl_up(x, off);
    if (lane >= off) x += tt;
  }
  __shared__ int ws[4];
  if (lane == 63) ws[wid] = x;
  __syncthreads();
  int wbase = 0;
  for (int w = 0; w < wid; ++w) wbase += ws[w];
  int run = partial[b] + wbase + (x - tsum);
#pragma unroll
  for (int q = 0; q < 4; ++q) {
    const int idx = base + q;
    if (idx < N) row_off[idx] = run;
    run += v[q];
  }
  if (b == 0 && t == 0) row_off[N] = E;
}

// ---------------------------------------------------------------------------
// K4: scatter PAYLOADS into CSR order (src id + 5 edge features), so the
// aggregate kernel streams them contiguously instead of gathering.
// ---------------------------------------------------------------------------
__global__ __launch_bounds__(256) void scatter_kernel(
    const int* __restrict__ dst, const int* __restrict__ src,
    const float* __restrict__ edge_fea, const int* __restrict__ row_off,
    const int* __restrict__ rank, int* __restrict__ src_csr,
    float* __restrict__ ef_csr, int E) {
  const int e = blockIdx.x * blockDim.x + threadIdx.x;
  if (e >= E) return;
  const int pos = row_off[dst[e]] + rank[e];
  src_csr[pos] = src[e];
#pragma unroll
  for (int k = 0; k < 5; ++k)
    ef_csr[(size_t)pos * 5 + k] = edge_fea[(size_t)e * 5 + k];
}

// ---------------------------------------------------------------------------
// K5: one wave per destination node, single pass (no segment-max: softmax is
// shift-invariant and logits are O(5), so exp() directly is safe).
//  A (lane-parallel): stream src_csr/ef_csr; logits from L2-resident el_er
//      via ee_h = <ef, g_h> + c0_h (algebraic collapse of edge projection);
//      p = exp(leaky(lg)); accumulate z, wef; stash p4,s in LDS.
//  B (serial, unrolled): ft[lane] += p * feat_p[s*64+lane]  (coalesced).
//  Epilogue: ftf = (wef @ W_edg)*inv + b_edg; fused [21]x[21,16] shfl matmul.
// ---------------------------------------------------------------------------
__global__ __launch_bounds__(256) void aggregate_kernel(
    const float* __restrict__ feat_p, const float* __restrict__ el_er,
    const int* __restrict__ src_csr, const float* __restrict__ ef_csr,
    const int* __restrict__ row_off,
    const float* __restrict__ W_edg, const float* __restrict__ b_edg,
    const float* __restrict__ attn_edg,
    const float* __restrict__ W_out, const float* __restrict__ b_out,
    const float* __restrict__ bias, float* __restrict__ out, int N) {
  __shared__ float p_lds[4][CAP * 4];
  __shared__ int   s_lds[4][CAP];

  const int wave = threadIdx.x >> 6;
  const int lane = threadIdx.x & 63;
  const int n = blockIdx.x * 4 + wave;
  if (n >= N) return;
  const int h = lane >> 4;
  const int d = lane & 15;

  // ee_h(ef) = c0[h] + sum_k ef[k]*g[k][h]   (collapsed edge-attention)
  float g[5][4];
  float c0[4];
#pragma unroll
  for (int hh = 0; hh < 4; ++hh) {
    float c = 0.f;
#pragma unroll
    for (int ed = 0; ed < 5; ++ed) c += b_edg[hh * 5 + ed] * attn_edg[hh * 5 + ed];
    c0[hh] = c;
#pragma unroll
    for (int k = 0; k < 5; ++k) {
      float s = 0.f;
#pragma unroll
      for (int ed = 0; ed < 5; ++ed)
        s += W_edg[k * 20 + hh * 5 + ed] * attn_edg[hh * 5 + ed];
      g[k][hh] = s;
    }
  }

  // epilogue constants for this lane
  float wcol[5];
  float be = 0.f;
  if (d < 5) {
    be = b_edg[h * 5 + d];
#pragma unroll
    for (int k = 0; k < 5; ++k) wcol[k] = W_edg[k * 20 + h * 5 + d];
  }

  const float4 er4 = *(const float4*)(el_er + (size_t)n * 8 + 4);
  const int beg = row_off[n];
  const int end = row_off[n + 1];
  const int deg = end - beg;

  float ft = 0.f, ftf = 0.f;

  if (deg <= CAP) {
    // ---- A: stream payloads, compute p, accumulate z & wef ----
    float4 z = make_float4(0.f, 0.f, 0.f, 0.f);
    float4 wef[5];
#pragma unroll
    for (int k = 0; k < 5; ++k) wef[k] = make_float4(0.f, 0.f, 0.f, 0.f);
    for (int j0 = 0; j0 < deg; j0 += 64) {
      const int j = j0 + lane;
      if (j < deg) {
        const int i = beg + j;
        const int s = src_csr[i];
        float ef[5];
#pragma unroll
        for (int k = 0; k < 5; ++k) ef[k] = ef_csr[(size_t)i * 5 + k];
        const float4 el4 = *(const float4*)(el_er + (size_t)s * 8);
        float lgh[4] = {el4.x + er4.x + c0[0], el4.y + er4.y + c0[1],
                        el4.z + er4.z + c0[2], el4.w + er4.w + c0[3]};
#pragma unroll
        for (int k = 0; k < 5; ++k) {
#pragma unroll
          for (int hh = 0; hh < 4; ++hh) lgh[hh] += ef[k] * g[k][hh];
        }
        float4 p;
        p.x = __expf(lgh[0] > 0.f ? lgh[0] : 0.2f * lgh[0]);
        p.y = __expf(lgh[1] > 0.f ? lgh[1] : 0.2f * lgh[1]);
        p.z = __expf(lgh[2] > 0.f ? lgh[2] : 0.2f * lgh[2]);
        p.w = __expf(lgh[3] > 0.f ? lgh[3] : 0.2f * lgh[3]);
        s_lds[wave][j] = s;
        *(float4*)&p_lds[wave][j * 4] = p;
        z.x += p.x; z.y += p.y; z.z += p.z; z.w += p.w;
#pragma unroll
        for (int k = 0; k < 5; ++k) {
          wef[k].x += p.x * ef[k];
          wef[k].y += p.y * ef[k];
          wef[k].z += p.z * ef[k];
          wef[k].w += p.w * ef[k];
        }
      }
    }
#pragma unroll
    for (int off = 32; off >= 1; off >>= 1) {
      z.x += __shfl_xor(z.x, off);
      z.y += __shfl_xor(z.y, off);
      z.z += __shfl_xor(z.z, off);
      z.w += __shfl_xor(z.w, off);
#pragma unroll
      for (int k = 0; k < 5; ++k) {
        wef[k].x += __shfl_xor(wef[k].x, off);
        wef[k].y += __shfl_xor(wef[k].y, off);
        wef[k].z += __shfl_xor(wef[k].z, off);
        wef[k].w += __shfl_xor(wef[k].w, off);
      }
    }

    // ---- B: serial weighted gather-accumulate (4-way unrolled) ----
    int j = 0;
    for (; j + 4 <= deg; j += 4) {
      const float p0 = p_lds[wave][(j + 0) * 4 + h];
      const float p1 = p_lds[wave][(j + 1) * 4 + h];
      const float p2 = p_lds[wave][(j + 2) * 4 + h];
      const float p3 = p_lds[wave][(j + 3) * 4 + h];
      const int s0 = s_lds[wave][j + 0];
      const int s1 = s_lds[wave][j + 1];
      const int s2 = s_lds[wave][j + 2];
      const int s3 = s_lds[wave][j + 3];
      const float f0 = feat_p[(size_t)s0 * 64 + lane];
      const float f1 = feat_p[(size_t)s1 * 64 + lane];
      const float f2 = feat_p[(size_t)s2 * 64 + lane];
      const float f3 = feat_p[(size_t)s3 * 64 + lane];
      ft += p0 * f0 + p1 * f1 + p2 * f2 + p3 * f3;
    }
    for (; j < deg; ++j) {
      const float p = p_lds[wave][j * 4 + h];
      const int s = s_lds[wave][j];
      ft += p * feat_p[(size_t)s * 64 + lane];
    }

    const float zh = (h == 0) ? z.x : (h == 1) ? z.y : (h == 2) ? z.z : z.w;
    const float inv = (zh > 0.f) ? 1.f / zh : 0.f;
    ft *= inv;
    if (d < 5) {
      float acc = 0.f;
#pragma unroll
      for (int k = 0; k < 5; ++k) {
        const float wk = (h == 0) ? wef[k].x : (h == 1) ? wef[k].y
                        : (h == 2) ? wef[k].z : wef[k].w;
        acc += wk * wcol[k];
      }
      ftf = acc * inv + ((zh > 0.f) ? be : 0.f);
    }
  } else {
    // ---- fallback: serial path (deg > CAP; rare) ----
    float z = 0.f;
    float wefh[5] = {0.f, 0.f, 0.f, 0.f, 0.f};
    const float erh = (h == 0) ? er4.x : (h == 1) ? er4.y : (h == 2) ? er4.z : er4.w;
    for (int i = beg; i < end; ++i) {
      const int s = src_csr[i];
      float ef[5];
#pragma unroll
      for (int k = 0; k < 5; ++k) ef[k] = ef_csr[(size_t)i * 5 + k];
      float lg = el_er[(size_t)s * 8 + h] + erh + c0[h];
#pragma unroll
      for (int k = 0; k < 5; ++k) lg += ef[k] * g[k][h];
      const float p = __expf(lg > 0.f ? lg : 0.2f * lg);
      z += p;
      ft += p * feat_p[(size_t)s * 64 + lane];
#pragma unroll
      for (int k = 0; k < 5; ++k) wefh[k] += p * ef[k];
    }
    const float inv = (z > 0.f) ? 1.f / z : 0.f;
    ft *= inv;
    if (d < 5) {
      float acc = 0.f;
#pragma unroll
      for (int k = 0; k < 5; ++k) acc += wefh[k] * wcol[k];
      ftf = acc * inv + ((z > 0.f) ? be : 0.f);
    }
  }

  // ---- epilogue: out[h][d] = cat(ftf,ft)[h][:] @ W_out + b ----
  float acc = b_out[d] + bias[lane];
#pragma unroll
  for (int k = 0; k < 5; ++k)
    acc += __shfl(ftf, h * 16 + k) * W_out[k * 16 + d];
#pragma unroll
  for (int k = 0; k < 16; ++k)
    acc += __shfl(ft, h * 16 + k) * W_out[(5 + k) * 16 + d];

  out[(size_t)n * 64 + lane] = acc;
}

// ---------------------------------------------------------------------------
extern "C" void kernel_launch(void* const* d_in, const int* in_sizes, int n_in,
                              void* d_out, int out_size, void* d_ws, size_t ws_size,
                              hipStream_t stream) {
  const float* feat     = (const float*)d_in[0];
  const float* edge_fea = (const float*)d_in[1];
  const int*   src      = (const int*)d_in[2];
  const int*   dst      = (const int*)d_in[3];
  const float* W_fc     = (const float*)d_in[4];
  const float* W_edg    = (const float*)d_in[5];
  const float* b_edg    = (const float*)d_in[6];
  const float* attn_l   = (const float*)d_in[7];
  const float* attn_r   = (const float*)d_in[8];
  const float* attn_edg = (const float*)d_in[9];
  const float* W_out    = (const float*)d_in[10];
  const float* b_out    = (const float*)d_in[11];
  const float* bias     = (const float*)d_in[12];

  const int N = in_sizes[0] / 64;
  const int E = in_sizes[2];
  float* out = (float*)d_out;

  char* ws = (char*)d_ws;
  size_t off = 0;
  auto alloc = [&](size_t bytes) -> void* {
    void* p = ws + off;
    off = (off + bytes + 255) & ~(size_t)255;
    return p;
  };
  float* feat_p  = (float*)alloc((size_t)N * 64 * 4);
  float* el_er   = (float*)alloc((size_t)N * 8 * 4);
  int*   deg     = (int*)alloc((size_t)N * 4);
  int*   rank    = (int*)alloc((size_t)E * 4);
  int*   row_off = (int*)alloc((size_t)(N + 1) * 4);
  int*   src_csr = (int*)alloc((size_t)E * 4);
  float* ef_csr  = (float*)alloc((size_t)E * 5 * 4);
  int*   partial = (int*)alloc((size_t)1024 * 4);
  (void)ws_size; (void)n_in; (void)out_size;

  hipMemsetAsync(deg, 0, (size_t)N * 4, stream);

  const int nblk_nodes = (N + 3) / 4;
  const int nblk_edges = (E + 255) / 256;
  const int nb_scan = (N + 1023) / 1024;

  node_proj_kernel<<<nblk_nodes, 256, 0, stream>>>(feat, W_fc, attn_l, attn_r,
                                                   feat_p, el_er, N);
  rank_kernel<<<nblk_edges, 256, 0, stream>>>(dst, deg, rank, E);
  scan_reduce_kernel<<<nb_scan, 256, 0, stream>>>(deg, partial, N);
  scan_partials_kernel<<<1, 256, 0, stream>>>(partial, nb_scan);
  scan_final_kernel<<<nb_scan, 256, 0, stream>>>(deg, partial, row_off, N, E);
  scatter_kernel<<<nblk_edges, 256, 0, stream>>>(dst, src, edge_fea, row_off,
                                                 rank, src_csr, ef_csr, E);
  aggregate_kernel<<<nblk_nodes, 256, 0, stream>>>(
      feat_p, el_er, src_csr, ef_csr, row_off, W_edg, b_edg, attn_edg, W_out,
      b_out, bias, out, N);
}

// Round 11
// 470.413 us; speedup vs baseline: 1.2879x; 1.2879x over previous
//
#include <hip/hip_runtime.h>
#include <hip/hip_bf16.h>
#include <math.h>

#define NHEADS 4
#define DOUT 16
#define EDIM 5
#define CAP 128   // per-node edge capacity for the LDS fast path

// ---------------------------------------------------------------------------
// K1: feat_p = feat @ W_fc  (N x 64 @ 64 x 64), fused el/er attention dots.
// ---------------------------------------------------------------------------
__global__ __launch_bounds__(256) void node_proj_kernel(
    const float* __restrict__ feat, const float* __restrict__ W_fc,
    const float* __restrict__ attn_l, const float* __restrict__ attn_r,
    float* __restrict__ feat_p, float* __restrict__ el_er, int N) {
  __shared__ float wfc[64 * 64];
  for (int i = threadIdx.x; i < 64 * 64; i += 256) wfc[i] = W_fc[i];
  __syncthreads();
  const int wid  = threadIdx.x >> 6;
  const int lane = threadIdx.x & 63;
  const int n = blockIdx.x * 4 + wid;
  if (n >= N) return;

  const float f = feat[(size_t)n * 64 + lane];
  float acc = 0.f;
#pragma unroll
  for (int k = 0; k < 64; ++k) {
    const float fk = __shfl(f, k);
    acc += fk * wfc[k * 64 + lane];
  }
  feat_p[(size_t)n * 64 + lane] = acc;

  float al = acc * attn_l[lane];
  float ar = acc * attn_r[lane];
#pragma unroll
  for (int off = 1; off < 16; off <<= 1) {
    al += __shfl_xor(al, off);
    ar += __shfl_xor(ar, off);
  }
  if ((lane & 15) == 0) {
    const int h = lane >> 4;
    el_er[(size_t)n * 8 + h]     = al;
    el_er[(size_t)n * 8 + 4 + h] = ar;
  }
}

// ---------------------------------------------------------------------------
// K2: dst histogram only (atomic return value = CSR rank).
// ---------------------------------------------------------------------------
__global__ __launch_bounds__(256) void rank_kernel(
    const int* __restrict__ dst, int* __restrict__ deg,
    int* __restrict__ rank, int E) {
  const int e = blockIdx.x * blockDim.x + threadIdx.x;
  if (e >= E) return;
  rank[e] = atomicAdd(&deg[dst[e]], 1);
}

// ---------------------------------------------------------------------------
// K3a/K3b/K3c: hierarchical exclusive scan of deg[N] -> row_off[N+1].
// ---------------------------------------------------------------------------
__global__ __launch_bounds__(256) void scan_reduce_kernel(
    const int* __restrict__ deg, int* __restrict__ partial, int N) {
  const int base = blockIdx.x * 1024;
  int sum = 0;
  for (int i = threadIdx.x; i < 1024; i += 256) {
    const int idx = base + i;
    sum += (idx < N) ? deg[idx] : 0;
  }
#pragma unroll
  for (int off = 32; off >= 1; off >>= 1) sum += __shfl_xor(sum, off);
  __shared__ int ws[4];
  if ((threadIdx.x & 63) == 0) ws[threadIdx.x >> 6] = sum;
  __syncthreads();
  if (threadIdx.x == 0) partial[blockIdx.x] = ws[0] + ws[1] + ws[2] + ws[3];
}

__global__ __launch_bounds__(256) void scan_partials_kernel(
    int* __restrict__ partial, int nb) {
  __shared__ int buf[256];
  __shared__ int carry_s;
  const int t = threadIdx.x;
  if (t == 0) carry_s = 0;
  __syncthreads();
  for (int base = 0; base < nb; base += 256) {
    const int i = base + t;
    const int v = (i < nb) ? partial[i] : 0;
    buf[t] = v;
    __syncthreads();
    for (int off = 1; off < 256; off <<= 1) {
      const int tmp = (t >= off) ? buf[t - off] : 0;
      __syncthreads();
      buf[t] += tmp;
      __syncthreads();
    }
    const int carry = carry_s;
    if (i < nb) partial[i] = carry + buf[t] - v;  // exclusive
    __syncthreads();
    if (t == 255) carry_s = carry + buf[255];
    __syncthreads();
  }
}

__global__ __launch_bounds__(256) void scan_final_kernel(
    const int* __restrict__ deg, const int* __restrict__ partial,
    int* __restrict__ row_off, int N, int E) {
  const int b = blockIdx.x;
  const int t = threadIdx.x;
  const int lane = t & 63;
  const int wid = t >> 6;
  const int base = b * 1024 + t * 4;
  int v[4];
#pragma unroll
  for (int q = 0; q < 4; ++q) {
    const int idx = base + q;
    v[q] = (idx < N) ? deg[idx] : 0;
  }
  const int tsum = v[0] + v[1] + v[2] + v[3];
  int x = tsum;
#pragma unroll
  for (int off = 1; off < 64; off <<= 1) {
    const int tt = __shfl_up(x, off);
    if (lane >= off) x += tt;
  }
  __shared__ int ws[4];
  if (lane == 63) ws[wid] = x;
  __syncthreads();
  int wbase = 0;
  for (int w = 0; w < wid; ++w) wbase += ws[w];
  int run = partial[b] + wbase + (x - tsum);
#pragma unroll
  for (int q = 0; q < 4; ++q) {
    const int idx = base + q;
    if (idx < N) row_off[idx] = run;
    run += v[q];
  }
  if (b == 0 && t == 0) row_off[N] = E;
}

// ---------------------------------------------------------------------------
// K4: scatter edge ids into CSR order (4 B/edge payload; no atomics).
// ---------------------------------------------------------------------------
__global__ __launch_bounds__(256) void scatter_kernel(
    const int* __restrict__ dst, const int* __restrict__ row_off,
    const int* __restrict__ rank, int* __restrict__ perm, int E) {
  const int e = blockIdx.x * blockDim.x + threadIdx.x;
  if (e >= E) return;
  perm[row_off[dst[e]] + rank[e]] = e;
}

// ---------------------------------------------------------------------------
// K5: one wave per destination node.
//  A (lane = j*4 + h, all 64 lanes active at deg>=16): gather perm/src/ef/el,
//     logit per (edge,head) via collapsed ee_h = <ef,g_h>+c0_h; p=exp(leaky);
//     z,wef reduced over j only (xor 4..32: ~50 inst vs 288 full butterfly);
//     p stashed in LDS [j*4+h], src in LDS.
//  B (lane = h*16 + d, serial, 8-way unrolled): ft += p * feat_p[s*64+lane].
//  Epilogue: ftf = (wef @ W_edg)*inv + b_edg; fused [21]x[21,16] shfl matmul.
// ---------------------------------------------------------------------------
__global__ __launch_bounds__(256) void aggregate_kernel(
    const float* __restrict__ feat_p, const float* __restrict__ el_er,
    const int* __restrict__ src, const float* __restrict__ edge_fea,
    const int* __restrict__ row_off, const int* __restrict__ perm,
    const float* __restrict__ W_edg, const float* __restrict__ b_edg,
    const float* __restrict__ attn_edg,
    const float* __restrict__ W_out, const float* __restrict__ b_out,
    const float* __restrict__ bias, float* __restrict__ out, int N) {
  __shared__ float p_lds[4][CAP * 4];
  __shared__ int   s_lds[4][CAP];

  const int wave = threadIdx.x >> 6;
  const int lane = threadIdx.x & 63;
  const int n = blockIdx.x * 4 + wave;
  if (n >= N) return;
  const int h = lane >> 4;   // B-layout head
  const int d = lane & 15;   // B-layout dim
  const int ja = lane >> 2;  // A-layout edge slot (0..15)
  const int ha = lane & 3;   // A-layout head

  // ee_h(ef) = c0[h] + sum_k ef[k]*g[k][h]   (collapsed edge-attention)
  float g[5][4];
  float c0[4];
#pragma unroll
  for (int hh = 0; hh < 4; ++hh) {
    float c = 0.f;
#pragma unroll
    for (int ed = 0; ed < 5; ++ed) c += b_edg[hh * 5 + ed] * attn_edg[hh * 5 + ed];
    c0[hh] = c;
#pragma unroll
    for (int k = 0; k < 5; ++k) {
      float s = 0.f;
#pragma unroll
      for (int ed = 0; ed < 5; ++ed)
        s += W_edg[k * 20 + hh * 5 + ed] * attn_edg[hh * 5 + ed];
      g[k][hh] = s;
    }
  }

  // epilogue constants for this lane (B-layout)
  float wcol[5];
  float be = 0.f;
  if (d < 5) {
    be = b_edg[h * 5 + d];
#pragma unroll
    for (int k = 0; k < 5; ++k) wcol[k] = W_edg[k * 20 + h * 5 + d];
  }

  const int beg = row_off[n];
  const int end = row_off[n + 1];
  const int deg = end - beg;

  float ft = 0.f, ftf = 0.f;

  if (deg <= CAP) {
    // ---- A: (j,h)-parallel logits + p; accumulate z, wef over own slots ----
    const float er_a = el_er[(size_t)n * 8 + 4 + ha];
    float z = 0.f;
    float wef[5] = {0.f, 0.f, 0.f, 0.f, 0.f};
    for (int j0 = 0; j0 < deg; j0 += 16) {
      const int j = j0 + ja;
      if (j < deg) {
        const int e = perm[beg + j];
        const int s = src[e];
        if (ha == 0) s_lds[wave][j] = s;
        float lg = el_er[(size_t)s * 8 + ha] + er_a + c0[ha];
        float ef[5];
#pragma unroll
        for (int k = 0; k < 5; ++k) {
          ef[k] = edge_fea[(size_t)e * 5 + k];
          lg += ef[k] * g[k][ha];
        }
        const float p = __expf(lg > 0.f ? lg : 0.2f * lg);
        p_lds[wave][j * 4 + ha] = p;
        z += p;
#pragma unroll
        for (int k = 0; k < 5; ++k) wef[k] += p * ef[k];
      }
    }
    // reduce over edge-slots (preserve ha = lane&3): xor 4,8,16,32
#pragma unroll
    for (int off = 4; off <= 32; off <<= 1) {
      z += __shfl_xor(z, off);
#pragma unroll
      for (int k = 0; k < 5; ++k) wef[k] += __shfl_xor(wef[k], off);
    }
    // transfer totals to B-layout: lane h (0..3) holds head-h totals
    const float zh = __shfl(z, h);
    float wk[5];
#pragma unroll
    for (int k = 0; k < 5; ++k) wk[k] = __shfl(wef[k], h);

    // ---- B: serial weighted gather-accumulate (8-way unrolled) ----
    int j = 0;
    for (; j + 8 <= deg; j += 8) {
      float pr[8];
      int   sr[8];
#pragma unroll
      for (int q = 0; q < 8; ++q) {
        pr[q] = p_lds[wave][(j + q) * 4 + h];
        sr[q] = s_lds[wave][j + q];
      }
      float fr[8];
#pragma unroll
      for (int q = 0; q < 8; ++q) fr[q] = feat_p[(size_t)sr[q] * 64 + lane];
#pragma unroll
      for (int q = 0; q < 8; ++q) ft += pr[q] * fr[q];
    }
    for (; j < deg; ++j) {
      const float p = p_lds[wave][j * 4 + h];
      const int s = s_lds[wave][j];
      ft += p * feat_p[(size_t)s * 64 + lane];
    }

    const float inv = (zh > 0.f) ? 1.f / zh : 0.f;
    ft *= inv;
    if (d < 5) {
      float acc = 0.f;
#pragma unroll
      for (int k = 0; k < 5; ++k) acc += wk[k] * wcol[k];
      ftf = acc * inv + ((zh > 0.f) ? be : 0.f);
    }
  } else {
    // ---- fallback: serial path (deg > CAP; rare) ----
    float z = 0.f;
    float wefh[5] = {0.f, 0.f, 0.f, 0.f, 0.f};
    const float erh = el_er[(size_t)n * 8 + 4 + h];
    for (int i = beg; i < end; ++i) {
      const int e = perm[i];
      const int s = src[e];
      float ef[5];
#pragma unroll
      for (int k = 0; k < 5; ++k) ef[k] = edge_fea[(size_t)e * 5 + k];
      float lg = el_er[(size_t)s * 8 + h] + erh + c0[h];
#pragma unroll
      for (int k = 0; k < 5; ++k) lg += ef[k] * g[k][h];
      const float p = __expf(lg > 0.f ? lg : 0.2f * lg);
      z += p;
      ft += p * feat_p[(size_t)s * 64 + lane];
#pragma unroll
      for (int k = 0; k < 5; ++k) wefh[k] += p * ef[k];
    }
    const float inv = (z > 0.f) ? 1.f / z : 0.f;
    ft *= inv;
    if (d < 5) {
      float acc = 0.f;
#pragma unroll
      for (int k = 0; k < 5; ++k) acc += wefh[k] * wcol[k];
      ftf = acc * inv + ((z > 0.f) ? be : 0.f);
    }
  }

  // ---- epilogue: out[h][d] = cat(ftf,ft)[h][:] @ W_out + b ----
  float acc = b_out[d] + bias[lane];
#pragma unroll
  for (int k = 0; k < 5; ++k)
    acc += __shfl(ftf, h * 16 + k) * W_out[k * 16 + d];
#pragma unroll
  for (int k = 0; k < 16; ++k)
    acc += __shfl(ft, h * 16 + k) * W_out[(5 + k) * 16 + d];

  out[(size_t)n * 64 + lane] = acc;
}

// ---------------------------------------------------------------------------
extern "C" void kernel_launch(void* const* d_in, const int* in_sizes, int n_in,
                              void* d_out, int out_size, void* d_ws, size_t ws_size,
                              hipStream_t stream) {
  const float* feat     = (const float*)d_in[0];
  const float* edge_fea = (const float*)d_in[1];
  const int*   src      = (const int*)d_in[2];
  const int*   dst      = (const int*)d_in[3];
  const float* W_fc     = (const float*)d_in[4];
  const float* W_edg    = (const float*)d_in[5];
  const float* b_edg    = (const float*)d_in[6];
  const float* attn_l   = (const float*)d_in[7];
  const float* attn_r   = (const float*)d_in[8];
  const float* attn_edg = (const float*)d_in[9];
  const float* W_out    = (const float*)d_in[10];
  const float* b_out    = (const float*)d_in[11];
  const float* bias     = (const float*)d_in[12];

  const int N = in_sizes[0] / 64;
  const int E = in_sizes[2];
  float* out = (float*)d_out;

  char* ws = (char*)d_ws;
  size_t off = 0;
  auto alloc = [&](size_t bytes) -> void* {
    void* p = ws + off;
    off = (off + bytes + 255) & ~(size_t)255;
    return p;
  };
  float* feat_p  = (float*)alloc((size_t)N * 64 * 4);
  float* el_er   = (float*)alloc((size_t)N * 8 * 4);
  int*   deg     = (int*)alloc((size_t)N * 4);
  int*   rank    = (int*)alloc((size_t)E * 4);
  int*   row_off = (int*)alloc((size_t)(N + 1) * 4);
  int*   perm    = (int*)alloc((size_t)E * 4);
  int*   partial = (int*)alloc((size_t)1024 * 4);
  (void)ws_size; (void)n_in; (void)out_size;

  hipMemsetAsync(deg, 0, (size_t)N * 4, stream);

  const int nblk_nodes = (N + 3) / 4;
  const int nblk_edges = (E + 255) / 256;
  const int nb_scan = (N + 1023) / 1024;

  node_proj_kernel<<<nblk_nodes, 256, 0, stream>>>(feat, W_fc, attn_l, attn_r,
                                                   feat_p, el_er, N);
  rank_kernel<<<nblk_edges, 256, 0, stream>>>(dst, deg, rank, E);
  scan_reduce_kernel<<<nb_scan, 256, 0, stream>>>(deg, partial, N);
  scan_partials_kernel<<<1, 256, 0, stream>>>(partial, nb_scan);
  scan_final_kernel<<<nb_scan, 256, 0, stream>>>(deg, partial, row_off, N, E);
  scatter_kernel<<<nblk_edges, 256, 0, stream>>>(dst, row_off, rank, perm, E);
  aggregate_kernel<<<nblk_nodes, 256, 0, stream>>>(
      feat_p, el_er, src, edge_fea, row_off, perm, W_edg, b_edg, attn_edg,
      W_out, b_out, bias, out, N);
}

// Round 16
// 444.221 us; speedup vs baseline: 1.3638x; 1.0590x over previous
//
#include <hip/hip_runtime.h>
#include <hip/hip_bf16.h>
#include <math.h>

#define NHEADS 4
#define DOUT 16
#define EDIM 5
#define CAP 128   // per-node edge capacity for the LDS fast path

// ---------------------------------------------------------------------------
// K1: feat_p = feat @ W_fc  (N x 64 @ 64 x 64), fused el/er attention dots.
// Block 0 additionally precomputes the collapsed edge-attention constants:
//   cpre[k*4+h] = sum_ed W_edg[k][h,ed]*attn_edg[h,ed]   (k<5)
//   cpre[20+h]  = sum_ed b_edg[h,ed]*attn_edg[h,ed]
// ---------------------------------------------------------------------------
__global__ __launch_bounds__(256) void node_proj_kernel(
    const float* __restrict__ feat, const float* __restrict__ W_fc,
    const float* __restrict__ attn_l, const float* __restrict__ attn_r,
    const float* __restrict__ W_edg, const float* __restrict__ b_edg,
    const float* __restrict__ attn_edg, float* __restrict__ cpre,
    float* __restrict__ feat_p, float* __restrict__ el_er, int N) {
  if (blockIdx.x == 0 && threadIdx.x < 24) {
    const int t = threadIdx.x;
    if (t < 20) {
      const int k = t >> 2, hh = t & 3;
      float s = 0.f;
#pragma unroll
      for (int ed = 0; ed < 5; ++ed)
        s += W_edg[k * 20 + hh * 5 + ed] * attn_edg[hh * 5 + ed];
      cpre[t] = s;
    } else {
      const int hh = t - 20;
      float c = 0.f;
#pragma unroll
      for (int ed = 0; ed < 5; ++ed)
        c += b_edg[hh * 5 + ed] * attn_edg[hh * 5 + ed];
      cpre[t] = c;
    }
  }

  __shared__ float wfc[64 * 64];
  for (int i = threadIdx.x; i < 64 * 64; i += 256) wfc[i] = W_fc[i];
  __syncthreads();
  const int wid  = threadIdx.x >> 6;
  const int lane = threadIdx.x & 63;
  const int n = blockIdx.x * 4 + wid;
  if (n >= N) return;

  const float f = feat[(size_t)n * 64 + lane];
  float acc = 0.f;
#pragma unroll
  for (int k = 0; k < 64; ++k) {
    const float fk = __shfl(f, k);
    acc += fk * wfc[k * 64 + lane];
  }
  feat_p[(size_t)n * 64 + lane] = acc;

  float al = acc * attn_l[lane];
  float ar = acc * attn_r[lane];
#pragma unroll
  for (int off = 1; off < 16; off <<= 1) {
    al += __shfl_xor(al, off);
    ar += __shfl_xor(ar, off);
  }
  if ((lane & 15) == 0) {
    const int h = lane >> 4;
    el_er[(size_t)n * 8 + h]     = al;
    el_er[(size_t)n * 8 + 4 + h] = ar;
  }
}

// ---------------------------------------------------------------------------
// K2: dst histogram only (atomic return value = CSR rank).
// ---------------------------------------------------------------------------
__global__ __launch_bounds__(256) void rank_kernel(
    const int* __restrict__ dst, int* __restrict__ deg,
    int* __restrict__ rank, int E) {
  const int e = blockIdx.x * blockDim.x + threadIdx.x;
  if (e >= E) return;
  rank[e] = atomicAdd(&deg[dst[e]], 1);
}

// ---------------------------------------------------------------------------
// K3a: per-1024-chunk sums of deg[N].
// ---------------------------------------------------------------------------
__global__ __launch_bounds__(256) void scan_reduce_kernel(
    const int* __restrict__ deg, int* __restrict__ partial, int N) {
  const int base = blockIdx.x * 1024;
  int sum = 0;
  for (int i = threadIdx.x; i < 1024; i += 256) {
    const int idx = base + i;
    sum += (idx < N) ? deg[idx] : 0;
  }
#pragma unroll
  for (int off = 32; off >= 1; off >>= 1) sum += __shfl_xor(sum, off);
  __shared__ int ws[4];
  if ((threadIdx.x & 63) == 0) ws[threadIdx.x >> 6] = sum;
  __syncthreads();
  if (threadIdx.x == 0) partial[blockIdx.x] = ws[0] + ws[1] + ws[2] + ws[3];
}

// ---------------------------------------------------------------------------
// K3b: final scan. Wave 0 of each block computes the block's carry-in by a
// masked sum over the (<=~100) raw partials; rest is the usual in-block scan.
// ---------------------------------------------------------------------------
__global__ __launch_bounds__(256) void scan_final_kernel(
    const int* __restrict__ deg, const int* __restrict__ partial,
    int* __restrict__ row_off, int N, int E, int nb) {
  const int b = blockIdx.x;
  const int t = threadIdx.x;
  const int lane = t & 63;
  const int wid = t >> 6;
  const int base = b * 1024 + t * 4;
  int v[4];
#pragma unroll
  for (int q = 0; q < 4; ++q) {
    const int idx = base + q;
    v[q] = (idx < N) ? deg[idx] : 0;
  }
  const int tsum = v[0] + v[1] + v[2] + v[3];
  int x = tsum;
#pragma unroll
  for (int off = 1; off < 64; off <<= 1) {
    const int tt = __shfl_up(x, off);
    if (lane >= off) x += tt;
  }
  __shared__ int ws[4];
  __shared__ int base_s;
  if (lane == 63) ws[wid] = x;
  if (wid == 0) {
    int s = 0;
    for (int i = lane; i < nb; i += 64) s += (i < b) ? partial[i] : 0;
#pragma unroll
    for (int off = 32; off >= 1; off >>= 1) s += __shfl_xor(s, off);
    if (lane == 0) base_s = s;
  }
  __syncthreads();
  int wbase = 0;
  for (int w = 0; w < wid; ++w) wbase += ws[w];
  int run = base_s + wbase + (x - tsum);
#pragma unroll
  for (int q = 0; q < 4; ++q) {
    const int idx = base + q;
    if (idx < N) row_off[idx] = run;
    run += v[q];
  }
  if (b == 0 && t == 0) row_off[N] = E;
}

// ---------------------------------------------------------------------------
// K4: scatter edge ids into CSR order (4 B/edge payload; no atomics).
// ---------------------------------------------------------------------------
__global__ __launch_bounds__(256) void scatter_kernel(
    const int* __restrict__ dst, const int* __restrict__ row_off,
    const int* __restrict__ rank, int* __restrict__ perm, int E) {
  const int e = blockIdx.x * blockDim.x + threadIdx.x;
  if (e >= E) return;
  perm[row_off[dst[e]] + rank[e]] = e;
}

// ---------------------------------------------------------------------------
// K5: one wave per destination node.
//  A (lane = j*4 + h): gather perm/src/ef/el; logit via precomputed ga/c0a;
//     p=exp(leaky); z,wef reduced over j (xor 4..32); p,src stashed in LDS.
//  B (lane = h*16 + d, serial, 8-way unrolled): ft += p * feat_p[s*64+lane].
//  Epilogue: ftf = (wef @ W_edg)*inv + b_edg; fused [21]x[21,16] shfl matmul.
// ---------------------------------------------------------------------------
__global__ __launch_bounds__(256) void aggregate_kernel(
    const float* __restrict__ feat_p, const float* __restrict__ el_er,
    const int* __restrict__ src, const float* __restrict__ edge_fea,
    const int* __restrict__ row_off, const int* __restrict__ perm,
    const float* __restrict__ cpre,
    const float* __restrict__ W_edg, const float* __restrict__ b_edg,
    const float* __restrict__ W_out, const float* __restrict__ b_out,
    const float* __restrict__ bias, float* __restrict__ out, int N) {
  __shared__ float p_lds[4][CAP * 4];
  __shared__ int   s_lds[4][CAP];

  const int wave = threadIdx.x >> 6;
  const int lane = threadIdx.x & 63;
  const int n = blockIdx.x * 4 + wave;
  if (n >= N) return;
  const int h = lane >> 4;   // B-layout head
  const int d = lane & 15;   // B-layout dim
  const int ja = lane >> 2;  // A-layout edge slot (0..15)
  const int ha = lane & 3;   // A-layout head

  // per-lane collapsed constants (A-layout column ha)
  float ga[5];
#pragma unroll
  for (int k = 0; k < 5; ++k) ga[k] = cpre[k * 4 + ha];
  const float c0a = cpre[20 + ha];

  // epilogue constants for this lane (B-layout)
  float wcol[5];
  float be = 0.f;
  if (d < 5) {
    be = b_edg[h * 5 + d];
#pragma unroll
    for (int k = 0; k < 5; ++k) wcol[k] = W_edg[k * 20 + h * 5 + d];
  }

  const int beg = row_off[n];
  const int end = row_off[n + 1];
  const int deg = end - beg;

  float ft = 0.f, ftf = 0.f;

  if (deg <= CAP) {
    // ---- A: (j,h)-parallel logits + p; accumulate z, wef over own slots ----
    const float er_a = el_er[(size_t)n * 8 + 4 + ha];
    float z = 0.f;
    float wef[5] = {0.f, 0.f, 0.f, 0.f, 0.f};
    for (int j0 = 0; j0 < deg; j0 += 16) {
      const int j = j0 + ja;
      if (j < deg) {
        const int e = perm[beg + j];
        const int s = src[e];
        if (ha == 0) s_lds[wave][j] = s;
        float lg = el_er[(size_t)s * 8 + ha] + er_a + c0a;
        float ef[5];
#pragma unroll
        for (int k = 0; k < 5; ++k) {
          ef[k] = edge_fea[(size_t)e * 5 + k];
          lg += ef[k] * ga[k];
        }
        const float p = __expf(lg > 0.f ? lg : 0.2f * lg);
        p_lds[wave][j * 4 + ha] = p;
        z += p;
#pragma unroll
        for (int k = 0; k < 5; ++k) wef[k] += p * ef[k];
      }
    }
    // reduce over edge-slots (preserve ha = lane&3): xor 4,8,16,32
#pragma unroll
    for (int off = 4; off <= 32; off <<= 1) {
      z += __shfl_xor(z, off);
#pragma unroll
      for (int k = 0; k < 5; ++k) wef[k] += __shfl_xor(wef[k], off);
    }
    // transfer totals to B-layout: lane h (0..3) holds head-h totals
    const float zh = __shfl(z, h);
    float wk[5];
#pragma unroll
    for (int k = 0; k < 5; ++k) wk[k] = __shfl(wef[k], h);

    // ---- B: serial weighted gather-accumulate (8-way unrolled) ----
    int j = 0;
    for (; j + 8 <= deg; j += 8) {
      float pr[8];
      int   sr[8];
#pragma unroll
      for (int q = 0; q < 8; ++q) {
        pr[q] = p_lds[wave][(j + q) * 4 + h];
        sr[q] = s_lds[wave][j + q];
      }
      float fr[8];
#pragma unroll
      for (int q = 0; q < 8; ++q) fr[q] = feat_p[(size_t)sr[q] * 64 + lane];
#pragma unroll
      for (int q = 0; q < 8; ++q) ft += pr[q] * fr[q];
    }
    for (; j < deg; ++j) {
      const float p = p_lds[wave][j * 4 + h];
      const int s = s_lds[wave][j];
      ft += p * feat_p[(size_t)s * 64 + lane];
    }

    const float inv = (zh > 0.f) ? 1.f / zh : 0.f;
    ft *= inv;
    if (d < 5) {
      float acc = 0.f;
#pragma unroll
      for (int k = 0; k < 5; ++k) acc += wk[k] * wcol[k];
      ftf = acc * inv + ((zh > 0.f) ? be : 0.f);
    }
  } else {
    // ---- fallback: serial path (deg > CAP; rare) ----
    float gh[5];
#pragma unroll
    for (int k = 0; k < 5; ++k) gh[k] = cpre[k * 4 + h];
    const float c0h = cpre[20 + h];
    float z = 0.f;
    float wefh[5] = {0.f, 0.f, 0.f, 0.f, 0.f};
    const float erh = el_er[(size_t)n * 8 + 4 + h];
    for (int i = beg; i < end; ++i) {
      const int e = perm[i];
      const int s = src[e];
      float ef[5];
#pragma unroll
      for (int k = 0; k < 5; ++k) ef[k] = edge_fea[(size_t)e * 5 + k];
      float lg = el_er[(size_t)s * 8 + h] + erh + c0h;
#pragma unroll
      for (int k = 0; k < 5; ++k) lg += ef[k] * gh[k];
      const float p = __expf(lg > 0.f ? lg : 0.2f * lg);
      z += p;
      ft += p * feat_p[(size_t)s * 64 + lane];
#pragma unroll
      for (int k = 0; k < 5; ++k) wefh[k] += p * ef[k];
    }
    const float inv = (z > 0.f) ? 1.f / z : 0.f;
    ft *= inv;
    if (d < 5) {
      float acc = 0.f;
#pragma unroll
      for (int k = 0; k < 5; ++k) acc += wefh[k] * wcol[k];
      ftf = acc * inv + ((z > 0.f) ? be : 0.f);
    }
  }

  // ---- epilogue: out[h][d] = cat(ftf,ft)[h][:] @ W_out + b ----
  float acc = b_out[d] + bias[lane];
#pragma unroll
  for (int k = 0; k < 5; ++k)
    acc += __shfl(ftf, h * 16 + k) * W_out[k * 16 + d];
#pragma unroll
  for (int k = 0; k < 16; ++k)
    acc += __shfl(ft, h * 16 + k) * W_out[(5 + k) * 16 + d];

  out[(size_t)n * 64 + lane] = acc;
}

// ---------------------------------------------------------------------------
extern "C" void kernel_launch(void* const* d_in, const int* in_sizes, int n_in,
                              void* d_out, int out_size, void* d_ws, size_t ws_size,
                              hipStream_t stream) {
  const float* feat     = (const float*)d_in[0];
  const float* edge_fea = (const float*)d_in[1];
  const int*   src      = (const int*)d_in[2];
  const int*   dst      = (const int*)d_in[3];
  const float* W_fc     = (const float*)d_in[4];
  const float* W_edg    = (const float*)d_in[5];
  const float* b_edg    = (const float*)d_in[6];
  const float* attn_l   = (const float*)d_in[7];
  const float* attn_r   = (const float*)d_in[8];
  const float* attn_edg = (const float*)d_in[9];
  const float* W_out    = (const float*)d_in[10];
  const float* b_out    = (const float*)d_in[11];
  const float* bias     = (const float*)d_in[12];

  const int N = in_sizes[0] / 64;
  const int E = in_sizes[2];
  float* out = (float*)d_out;

  char* ws = (char*)d_ws;
  size_t off = 0;
  auto alloc = [&](size_t bytes) -> void* {
    void* p = ws + off;
    off = (off + bytes + 255) & ~(size_t)255;
    return p;
  };
  float* feat_p  = (float*)alloc((size_t)N * 64 * 4);
  float* el_er   = (float*)alloc((size_t)N * 8 * 4);
  int*   deg     = (int*)alloc((size_t)N * 4);
  int*   rank    = (int*)alloc((size_t)E * 4);
  int*   row_off = (int*)alloc((size_t)(N + 1) * 4);
  int*   perm    = (int*)alloc((size_t)E * 4);
  int*   partial = (int*)alloc((size_t)1024 * 4);
  float* cpre    = (float*)alloc((size_t)32 * 4);
  (void)ws_size; (void)n_in; (void)out_size;

  hipMemsetAsync(deg, 0, (size_t)N * 4, stream);

  const int nblk_nodes = (N + 3) / 4;
  const int nblk_edges = (E + 255) / 256;
  const int nb_scan = (N + 1023) / 1024;

  node_proj_kernel<<<nblk_nodes, 256, 0, stream>>>(
      feat, W_fc, attn_l, attn_r, W_edg, b_edg, attn_edg, cpre,
      feat_p, el_er, N);
  rank_kernel<<<nblk_edges, 256, 0, stream>>>(dst, deg, rank, E);
  scan_reduce_kernel<<<nb_scan, 256, 0, stream>>>(deg, partial, N);
  scan_final_kernel<<<nb_scan, 256, 0, stream>>>(deg, partial, row_off, N, E,
                                                 nb_scan);
  scatter_kernel<<<nblk_edges, 256, 0, stream>>>(dst, row_off, rank, perm, E);
  aggregate_kernel<<<nblk_nodes, 256, 0, stream>>>(
      feat_p, el_er, src, edge_fea, row_off, perm, cpre, W_edg, b_edg,
      W_out, b_out, bias, out, N);
}